// Round 2
// baseline (1647.497 us; speedup 1.0000x reference)
//
#include <hip/hip_runtime.h>
#include <math.h>

#define MTOK 16384
#define NEXP 256
#define KDIM 7168

#define BM 128
#define BN 64
#define BK 16
#define LDA 132   // BM + 4 pad
#define LDB 68    // BN + 4 pad

// ---------- GEMM, f64 accumulation: L[m][e] = x[m,:] . W[e,:] (exact-ish) ----------
__launch_bounds__(256)
__global__ void gemm_f64_k(const float* __restrict__ X,
                           const float* __restrict__ W,
                           double* __restrict__ L) {
    __shared__ float As[BK][LDA];  // [k][m]
    __shared__ float Bs[BK][LDB];  // [k][n]
    const int tid = threadIdx.x;
    const int m0 = blockIdx.x * BM;
    const int n0 = blockIdx.y * BN;

    const int lr = tid >> 2;   // 0..63
    const int lc = tid & 3;    // 0..3 (float4 chunk)
    const int tn = tid & 15;   // n = tn*4
    const int tm = tid >> 4;   // m = tm*8

    const float* xg = X + (size_t)m0 * KDIM + lc * 4;
    const float* wg = W + (size_t)n0 * KDIM + lc * 4;

    double acc[8][4];
#pragma unroll
    for (int i = 0; i < 8; ++i)
#pragma unroll
        for (int j = 0; j < 4; ++j) acc[i][j] = 0.0;

    for (int k0 = 0; k0 < KDIM; k0 += BK) {
        float4 a0 = *(const float4*)(xg + (size_t)lr * KDIM + k0);
        float4 a1 = *(const float4*)(xg + (size_t)(lr + 64) * KDIM + k0);
        float4 b0 = *(const float4*)(wg + (size_t)lr * KDIM + k0);
        __syncthreads();
        As[lc * 4 + 0][lr] = a0.x;      As[lc * 4 + 1][lr] = a0.y;
        As[lc * 4 + 2][lr] = a0.z;      As[lc * 4 + 3][lr] = a0.w;
        As[lc * 4 + 0][lr + 64] = a1.x; As[lc * 4 + 1][lr + 64] = a1.y;
        As[lc * 4 + 2][lr + 64] = a1.z; As[lc * 4 + 3][lr + 64] = a1.w;
        Bs[lc * 4 + 0][lr] = b0.x;      Bs[lc * 4 + 1][lr] = b0.y;
        Bs[lc * 4 + 2][lr] = b0.z;      Bs[lc * 4 + 3][lr] = b0.w;
        __syncthreads();
#pragma unroll
        for (int k = 0; k < BK; ++k) {
            float4 av0 = *(const float4*)&As[k][tm * 8];
            float4 av1 = *(const float4*)&As[k][tm * 8 + 4];
            float4 bv  = *(const float4*)&Bs[k][tn * 4];
            double ad[8] = {(double)av0.x, (double)av0.y, (double)av0.z, (double)av0.w,
                            (double)av1.x, (double)av1.y, (double)av1.z, (double)av1.w};
            double bd[4] = {(double)bv.x, (double)bv.y, (double)bv.z, (double)bv.w};
#pragma unroll
            for (int i = 0; i < 8; ++i)
#pragma unroll
                for (int j = 0; j < 4; ++j)
                    acc[i][j] = fma(ad[i], bd[j], acc[i][j]);
        }
    }

#pragma unroll
    for (int i = 0; i < 8; ++i) {
        const int row = m0 + tm * 8 + i;
        double4 o;
        o.x = acc[i][0]; o.y = acc[i][1]; o.z = acc[i][2]; o.w = acc[i][3];
        *(double4*)(L + (size_t)row * NEXP + n0 + tn * 4) = o;
    }
}

// ---------- Routing in f64: one wave per token ----------
// lane l owns experts e0=l*4..l*4+3; group g = l>>3 (32 experts/group)
__launch_bounds__(256)
__global__ void route_k(const double* __restrict__ L,
                        const float* __restrict__ bias,
                        float* __restrict__ out) {
    __shared__ double sraw[4][256];
    const int wv   = threadIdx.x >> 6;
    const int lane = threadIdx.x & 63;
    const int token = blockIdx.x * 4 + wv;
    const double NINF = -__builtin_inf();

    const double* row = L + (size_t)token * NEXP;
    const int e0 = lane * 4;
    double4 l4 = *(const double4*)(row + e0);

    double s0 = 1.0 / (1.0 + exp(-l4.x));
    double s1 = 1.0 / (1.0 + exp(-l4.y));
    double s2 = 1.0 / (1.0 + exp(-l4.z));
    double s3 = 1.0 / (1.0 + exp(-l4.w));
    sraw[wv][e0 + 0] = s0;  sraw[wv][e0 + 1] = s1;
    sraw[wv][e0 + 2] = s2;  sraw[wv][e0 + 3] = s3;

    float4 bi4 = *(const float4*)(bias + e0);
    double b0 = s0 + (double)bi4.x;
    double b1 = s1 + (double)bi4.y;
    double b2 = s2 + (double)bi4.z;
    double b3 = s3 + (double)bi4.w;

    // per-lane top-2 of 4 biased values
    double m1 = b0, m2 = NINF;
    if (b1 > m1) { m2 = m1; m1 = b1; } else if (b1 > m2) m2 = b1;
    if (b2 > m1) { m2 = m1; m1 = b2; } else if (b2 > m2) m2 = b2;
    if (b3 > m1) { m2 = m1; m1 = b3; } else if (b3 > m2) m2 = b3;
    // merge across the 8 lanes of this group
#pragma unroll
    for (int w = 1; w <= 4; w <<= 1) {
        double o1 = __shfl_xor(m1, w);
        double o2 = __shfl_xor(m2, w);
        double nm1 = fmax(m1, o1);
        double nm2 = fmax(fmin(m1, o1), fmax(m2, o2));
        m1 = nm1; m2 = nm2;
    }
    const double gs = m1 + m2;
    const int g = lane >> 3;

    // rank my group among 8 (stable)
    int rank = 0;
#pragma unroll
    for (int j = 0; j < 8; ++j) {
        double gj = __shfl(gs, j * 8);
        rank += (gj > gs) || (gj == gs && j < g);
    }
    if (rank >= 4) { b0 = NINF; b1 = NINF; b2 = NINF; b3 = NINF; }

    // stable top-8 over masked biased scores
    int myidx = 0;
#pragma unroll
    for (int it = 0; it < 8; ++it) {
        double bv = b0; int bi = e0;
        if (b1 > bv) { bv = b1; bi = e0 + 1; }
        if (b2 > bv) { bv = b2; bi = e0 + 2; }
        if (b3 > bv) { bv = b3; bi = e0 + 3; }
#pragma unroll
        for (int w = 1; w < 64; w <<= 1) {
            double ov = __shfl_xor(bv, w);
            int    oi = __shfl_xor(bi, w);
            if (ov > bv || (ov == bv && oi < bi)) { bv = ov; bi = oi; }
        }
        if (lane == it) myidx = bi;
        if ((bi >> 2) == lane) {
            switch (bi & 3) {
                case 0: b0 = NINF; break;
                case 1: b1 = NINF; break;
                case 2: b2 = NINF; break;
                case 3: b3 = NINF; break;
            }
        }
    }

    __syncthreads();

    double wval = (lane < 8) ? sraw[wv][myidx] : 0.0;
    double s = wval;
    s += __shfl_xor(s, 1);
    s += __shfl_xor(s, 2);
    s += __shfl_xor(s, 4);
    if (lane < 8) {
        float wout = (float)(wval / (s + 1e-20) * 2.5);
        out[(size_t)token * 8 + lane] = wout;
        out[(size_t)MTOK * 8 + (size_t)token * 8 + lane] = (float)myidx;
    }
}

extern "C" void kernel_launch(void* const* d_in, const int* in_sizes, int n_in,
                              void* d_out, int out_size, void* d_ws, size_t ws_size,
                              hipStream_t stream) {
    const float* X    = (const float*)d_in[0];   // [16384, 7168]
    const float* W    = (const float*)d_in[1];   // [256, 7168]
    const float* bias = (const float*)d_in[2];   // [256]
    float* out = (float*)d_out;
    double* L  = (double*)d_ws;                  // logits f64 [16384, 256] = 33.5 MB

    dim3 g1(MTOK / BM, NEXP / BN);               // 128 x 4
    gemm_f64_k<<<g1, 256, 0, stream>>>(X, W, L);
    route_k<<<MTOK / 4, 256, 0, stream>>>(L, bias, out);
}